// Round 17
// baseline (3470.103 us; speedup 1.0000x reference)
//
#include <hip/hip_runtime.h>
#include <hip/hip_fp16.h>

#define BB 64
#define SS 1024
#define MEL 60
#define HH 180
#define G4 720    // 4*H
#define G4P 768   // 48 col-groups of 16
#define NCG 48
#define NKS 6     // k-steps of 32 (K padded to 192)
#define KP 192
#define NL 4
#define NPOST 8192
#define NOUT 300
#define NOUTP 320
#define KSPL 16
#define TT 128
#define CH 64
#define NCH (SS / CH)
#define HCH 32    // half-chunk for LDS pre

typedef _Float16 f16x8 __attribute__((ext_vector_type(8)));
typedef float f32x4 __attribute__((ext_vector_type(4)));

#if defined(__has_builtin)
#if __has_builtin(__builtin_amdgcn_rcpf)
#define HAVE_RCPF 1
#endif
#endif
#ifndef HAVE_RCPF
#define HAVE_RCPF 0
#endif

__device__ __forceinline__ float fast_rcp(float x) {
#if HAVE_RCPF
    return __builtin_amdgcn_rcpf(x);
#else
    return 1.f / x;
#endif
}
__device__ __forceinline__ float fsigm(float x) { return fast_rcp(1.f + __expf(-x)); }
__device__ __forceinline__ float ftanh_(float x) { return 1.f - 2.f * fast_rcp(__expf(2.f * x) + 1.f); }

union WU { uint4 u; f16x8 f; };

// ---------------- prep ----------------
// wmf[l][cg][ks][lane]: col = cg*16+(lane&15) (linear col), k = ks*32+(lane>>4)*8+j. (r7/r15-verified)
__global__ void prep_wmf(const float* __restrict__ whh, uint4* __restrict__ wmf) {
    int idx = blockIdx.x * blockDim.x + threadIdx.x;
    int total = NL * NCG * NKS * 64;
    if (idx >= total) return;
    int l = idx / (NCG * NKS * 64);
    int r = idx % (NCG * NKS * 64);
    int cg = r / (NKS * 64);
    int r2 = r % (NKS * 64);
    int ks = r2 / 64, lane = r2 % 64;
    int col = cg * 16 + (lane & 15);
    unsigned short v[8];
    #pragma unroll
    for (int j = 0; j < 8; ++j) {
        int k = ks * 32 + ((lane >> 4) << 3) + j;
        float f = (k < HH && col < G4) ? whh[((size_t)l * G4 + col) * HH + k] : 0.f;
        v[j] = __half_as_ushort(__float2half(f));
    }
    uint4 u;
    u.x = (unsigned)v[0] | ((unsigned)v[1] << 16);
    u.y = (unsigned)v[2] | ((unsigned)v[3] << 16);
    u.z = (unsigned)v[4] | ((unsigned)v[5] << 16);
    u.w = (unsigned)v[6] | ((unsigned)v[7] << 16);
    wmf[idx] = u;
}

// wmfI: identical transform on wih (B-frags for the in-kernel pre-GEMM).
__global__ void prep_wmfI(const float* __restrict__ wih0, const float* __restrict__ wih_rest,
                          uint4* __restrict__ wmfI) {
    int idx = blockIdx.x * blockDim.x + threadIdx.x;
    int total = NL * NCG * NKS * 64;
    if (idx >= total) return;
    int l = idx / (NCG * NKS * 64);
    int r = idx % (NCG * NKS * 64);
    int cg = r / (NKS * 64);
    int r2 = r % (NKS * 64);
    int ks = r2 / 64, lane = r2 % 64;
    int col = cg * 16 + (lane & 15);
    int K = (l == 0) ? MEL : HH;
    unsigned short v[8];
    #pragma unroll
    for (int j = 0; j < 8; ++j) {
        int k = ks * 32 + ((lane >> 4) << 3) + j;
        float f = 0.f;
        if (col < G4 && k < K)
            f = (l == 0) ? wih0[(size_t)col * MEL + k]
                         : wih_rest[((size_t)(l - 1) * G4 + col) * HH + k];
        v[j] = __half_as_ushort(__float2half(f));
    }
    uint4 u;
    u.x = (unsigned)v[0] | ((unsigned)v[1] << 16);
    u.y = (unsigned)v[2] | ((unsigned)v[3] << 16);
    u.z = (unsigned)v[4] | ((unsigned)v[5] << 16);
    u.w = (unsigned)v[6] | ((unsigned)v[7] << 16);
    wmfI[idx] = u;
}

__global__ void prep_bsum(const float* __restrict__ bih, const float* __restrict__ bhh,
                          float* __restrict__ bsum) {
    int idx = blockIdx.x * blockDim.x + threadIdx.x;
    if (idx >= NL * G4) return;
    bsum[idx] = bih[idx] + bhh[idx];
}

// ---------------- mel smooth residual block ----------------
template <typename TIN>
__global__ __launch_bounds__(256) void mel_block(const TIN* __restrict__ in,
                                                 __half* __restrict__ out,
                                                 const float* __restrict__ w,
                                                 const float* __restrict__ bias) {
    __shared__ float xt[TT + 4][MEL];
    __shared__ float ws[900];
    __shared__ float bs[MEL];
    int bb = blockIdx.x;
    int t0 = blockIdx.y * TT;
    int tid = threadIdx.x;
    const TIN* inb = in + (size_t)bb * SS * MEL;
    for (int idx = tid; idx < (TT + 4) * MEL; idx += 256) {
        int tt = idx / MEL, ch = idx % MEL;
        int t = t0 + tt - 2;
        xt[tt][ch] = (t >= 0 && t < SS) ? (float)inb[(size_t)t * MEL + ch] : 0.f;
    }
    for (int idx = tid; idx < 900; idx += 256) ws[idx] = w[idx];
    if (tid < MEL) bs[tid] = bias[(tid % 3) * 20 + tid / 3];
    __syncthreads();
    for (int idx = tid; idx < TT * MEL; idx += 256) {
        int tt = idx / MEL, ch = idx % MEL;
        int i = ch / 3, j = ch % 3;
        int qb = 3 * i + (j - 1);
        float acc = bs[ch];
        #pragma unroll
        for (int c = 0; c < 3; ++c) {
            int q = qb + c;
            if (q >= 0 && q < MEL) {
                const float* wp = ws + ((j * 20 + i) * 3 + c) * 5;
                #pragma unroll
                for (int k = 0; k < 5; ++k) acc += xt[tt + k][q] * wp[k];
            }
        }
        out[(size_t)bb * SS * MEL + (size_t)(t0 + tt) * MEL + ch] =
            __float2half(acc + xt[tt + 2][ch]);
    }
}

// ---------------- fused LSTM: in-LDS pre-GEMM prologue + MFMA recurrent scan ----------------
struct ScanArgs {
    const __half* A[NL];     // h_{l-1} (or melF): [b][S][K]
    const uint4*  wmfi[NL];
    const uint4*  wmf[NL];
    const float*  bs[NL];
    __half*       hout[NL];
    float*        hst[NL];
    float*        cst[NL];
    int           K[NL];
    int           t0[NL];
};

__global__ __launch_bounds__(768) __attribute__((amdgpu_waves_per_eu(3, 3)))
void lstm_scan(ScanArgs sa) {
    int j = blockIdx.x >> 6, b = blockIdx.x & 63;
    int tid = threadIdx.x;
    int wv = tid >> 6, lane = tid & 63;
    int r0 = lane >> 4, cl = lane & 15;
    int t0 = sa.t0[j];
    int K = sa.K[j];
    const __half* Ab = sa.A[j] + ((size_t)b * SS + t0) * K;
    const uint4* wmfI = sa.wmfi[j];
    const uint4* wmf = sa.wmf[j];
    const float* bsum = sa.bs[j];
    __half* houtb = sa.hout[j] + ((size_t)b * SS + (size_t)t0) * HH;
    float* hstb = sa.hst[j] + b * HH;
    float* cstb = sa.cst[j] + b * HH;

    __shared__ __align__(16) unsigned short A_lds[HCH][200];   // 12.5 KB
    __shared__ __align__(16) unsigned short preL[HCH][728];    // 45.5 KB
    __shared__ __align__(16) unsigned short hs[KP];            // 384 B
    __shared__ float gates[G4P];                               // 3 KB

    // recurrent weights pinned in AGPRs: frees the arch-VGPR file for the prologue.
    uint4 wfr[24];
    #pragma unroll
    for (int q = 0; q < 4; ++q)
        #pragma unroll
        for (int ks = 0; ks < NKS; ++ks)
            wfr[q * NKS + ks] = wmf[(((size_t)(wv * 4 + q)) * NKS + ks) * 64 + lane];
    #pragma unroll
    for (int r = 0; r < 24; ++r)
        asm volatile("" : "+a"(wfr[r].x), "+a"(wfr[r].y), "+a"(wfr[r].z), "+a"(wfr[r].w));

    float c = 0.f, hlast = 0.f;
    if (tid < KP) {
        float hv = 0.f;
        if (t0 > 0 && tid < HH) { hv = hstb[tid]; c = cstb[tid]; }
        hs[tid] = __half_as_ushort(__float2half(hv));
    }

    int hoff = r0 << 4;
    for (int half = 0; half < 2; ++half) {
        __syncthreads();
        for (int idx = tid; idx < HCH * 100; idx += 768) {
            int row = idx / 100, kp2 = idx % 100;
            unsigned v = 0u;
            if (2 * kp2 < K)
                v = *(const unsigned*)(Ab + (size_t)(half * HCH + row) * K + 2 * kp2);
            *(unsigned*)&A_lds[row][2 * kp2] = v;
        }
        __syncthreads();
        // prologue: pre GEMM into preL (r14-verified MFMA mapping); wB hoisted over mt
        #pragma unroll
        for (int q = 0; q < 4; ++q) {
            int cgg = wv * 4 + q;
            int col = cgg * 16 + cl;
            uint4 wB[NKS];
            #pragma unroll
            for (int ks = 0; ks < NKS; ++ks)
                wB[ks] = wmfI[((size_t)cgg * NKS + ks) * 64 + lane];
            #pragma unroll
            for (int mt = 0; mt < 2; ++mt) {
                f32x4 acc = {0.f, 0.f, 0.f, 0.f};
                #pragma unroll
                for (int ks = 0; ks < NKS; ++ks) {
                    WU af, wb2;
                    af.u = *(const uint4*)((const char*)&A_lds[(mt << 4) + cl][0] + (ks << 6) + (r0 << 4));
                    wb2.u = wB[ks];
                    acc = __builtin_amdgcn_mfma_f32_16x16x32_f16(af.f, wb2.f, acc, 0, 0, 0);
                }
                if (col < G4) {
                    float bv = bsum[col];
                    #pragma unroll
                    for (int i = 0; i < 4; ++i) {
                        int tl = (mt << 4) + (r0 << 2) + i;
                        preL[tl][col] = __half_as_ushort(__float2half(acc[i] + bv));
                    }
                }
            }
        }
        __syncthreads();
        // 32-step recurrent loop (r15-verified body; pre from LDS)
        for (int tt = 0; tt < HCH; ++tt) {
            f16x8 hf[NKS];
            #pragma unroll
            for (int ks = 0; ks < NKS; ++ks) {
                WU hu;
                hu.u = *(const uint4*)((const char*)hs + (ks << 6) + hoff);
                hf[ks] = hu.f;
            }
            f32x4 a0 = {0.f,0.f,0.f,0.f}, a1 = a0, a2 = a0, a3 = a0;
            #pragma unroll
            for (int ks = 0; ks < NKS; ++ks) {
                WU w0, w1, w2, w3;
                w0.u = wfr[0 * NKS + ks]; w1.u = wfr[1 * NKS + ks];
                w2.u = wfr[2 * NKS + ks]; w3.u = wfr[3 * NKS + ks];
                a0 = __builtin_amdgcn_mfma_f32_16x16x32_f16(hf[ks], w0.f, a0, 0, 0, 0);
                a1 = __builtin_amdgcn_mfma_f32_16x16x32_f16(hf[ks], w1.f, a1, 0, 0, 0);
                a2 = __builtin_amdgcn_mfma_f32_16x16x32_f16(hf[ks], w2.f, a2, 0, 0, 0);
                a3 = __builtin_amdgcn_mfma_f32_16x16x32_f16(hf[ks], w3.f, a3, 0, 0, 0);
            }
            if (lane < 16) {
                gates[(wv * 4 + 0) * 16 + lane] = a0[0];
                gates[(wv * 4 + 1) * 16 + lane] = a1[0];
                gates[(wv * 4 + 2) * 16 + lane] = a2[0];
                gates[(wv * 4 + 3) * 16 + lane] = a3[0];
            }
            __syncthreads();
            if (tid < HH) {
                float gi = gates[tid]          + __half2float(__ushort_as_half(preL[tt][tid]));
                float gf = gates[HH + tid]     + __half2float(__ushort_as_half(preL[tt][HH + tid]));
                float gg = gates[2 * HH + tid] + __half2float(__ushort_as_half(preL[tt][2 * HH + tid]));
                float go = gates[3 * HH + tid] + __half2float(__ushort_as_half(preL[tt][3 * HH + tid]));
                float si = fsigm(gi);
                float sf = fsigm(gf);
                float so = fsigm(go);
                float tg = ftanh_(gg);
                c = sf * c + si * tg;
                float hn = so * ftanh_(c);
                __half hh = __float2half(hn);
                hs[tid] = __half_as_ushort(hh);
                hlast = __half2float(hh);
                houtb[(size_t)(half * HCH + tt) * HH + tid] = hh;
            }
            __syncthreads();
        }
    }
    if (tid < HH) { hstb[tid] = hlast; cstb[tid] = c; }
}

// ---------------- epilogue ----------------
__global__ void gather_last(const __half* __restrict__ hfin, const int* __restrict__ lens,
                            float* __restrict__ last) {
    int idx = blockIdx.x * blockDim.x + threadIdx.x;
    if (idx >= BB * HH) return;
    int b = idx / HH, d = idx % HH;
    int t = lens[b] - 1;
    t = t < 0 ? 0 : (t > SS - 1 ? SS - 1 : t);
    last[idx] = __half2float(hfin[((size_t)b * SS + t) * HH + d]);
}

__global__ __launch_bounds__(256) void post_gemm(const float* __restrict__ A,
                                                 const float* __restrict__ Bw,
                                                 const float* __restrict__ pb,
                                                 float* __restrict__ Cb) {
    __shared__ float As[16][68];
    __shared__ float Bs[16][68];
    int n0 = blockIdx.x * 64;
    int tid = threadIdx.x;
    int kk = tid & 15, q = tid >> 4;
    int tx = tid & 15, ty = tid >> 4;
    float acc[4][4];
    #pragma unroll
    for (int i = 0; i < 4; ++i)
        #pragma unroll
        for (int jj = 0; jj < 4; ++jj) acc[i][jj] = 0.f;
    for (int kt = 0; kt < 12; ++kt) {
        int kidx = kt * 16 + kk;
        bool kval = kidx < HH;
        #pragma unroll
        for (int r = 0; r < 4; ++r)
            As[kk][q + (r << 4)] = kval ? A[(size_t)(q + (r << 4)) * HH + kidx] : 0.f;
        #pragma unroll
        for (int r = 0; r < 4; ++r)
            Bs[kk][q + (r << 4)] = kval ? Bw[(size_t)(n0 + q + (r << 4)) * HH + kidx] : 0.f;
        __syncthreads();
        #pragma unroll
        for (int k = 0; k < 16; ++k) {
            float a[4], bv[4];
            #pragma unroll
            for (int i = 0; i < 4; ++i) a[i] = As[k][ty + (i << 4)];
            #pragma unroll
            for (int jj = 0; jj < 4; ++jj) bv[jj] = Bs[k][(tx << 2) + jj];
            #pragma unroll
            for (int i = 0; i < 4; ++i)
                #pragma unroll
                for (int jj = 0; jj < 4; ++jj) acc[i][jj] = fmaf(a[i], bv[jj], acc[i][jj]);
        }
        __syncthreads();
    }
    #pragma unroll
    for (int i = 0; i < 4; ++i) {
        int m = ty + (i << 4);
        #pragma unroll
        for (int jj = 0; jj < 4; ++jj) {
            int g = n0 + (tx << 2) + jj;
            float v = acc[i][jj] + pb[g];
            Cb[(size_t)m * NPOST + g] = v > 0.f ? v : 0.01f * v;
        }
    }
}

__global__ __launch_bounds__(256) void up_gemm(const float* __restrict__ A,
                                               const float* __restrict__ Bw,
                                               float* __restrict__ part) {
    __shared__ float As[16][68];
    __shared__ float Bs[16][68];
    int n0 = blockIdx.x * 64;
    int k0 = blockIdx.y * (NPOST / KSPL);
    float* Pb = part + (size_t)blockIdx.y * BB * NOUTP;
    int tid = threadIdx.x;
    int kk = tid & 15, q = tid >> 4;
    int tx = tid & 15, ty = tid >> 4;
    float acc[4][4];
    #pragma unroll
    for (int i = 0; i < 4; ++i)
        #pragma unroll
        for (int jj = 0; jj < 4; ++jj) acc[i][jj] = 0.f;
    for (int kt = 0; kt < (NPOST / KSPL) / 16; ++kt) {
        int kidx = k0 + kt * 16 + kk;
        #pragma unroll
        for (int r = 0; r < 4; ++r)
            As[kk][q + (r << 4)] = A[(size_t)(q + (r << 4)) * NPOST + kidx];
        #pragma unroll
        for (int r = 0; r < 4; ++r) {
            int g = n0 + q + (r << 4);
            Bs[kk][q + (r << 4)] = (g < NOUT) ? Bw[(size_t)g * NPOST + kidx] : 0.f;
        }
        __syncthreads();
        #pragma unroll
        for (int k = 0; k < 16; ++k) {
            float a[4], bv[4];
            #pragma unroll
            for (int i = 0; i < 4; ++i) a[i] = As[k][ty + (i << 4)];
            #pragma unroll
            for (int jj = 0; jj < 4; ++jj) bv[jj] = Bs[k][(tx << 2) + jj];
            #pragma unroll
            for (int i = 0; i < 4; ++i)
                #pragma unroll
                for (int jj = 0; jj < 4; ++jj) acc[i][jj] = fmaf(a[i], bv[jj], acc[i][jj]);
        }
        __syncthreads();
    }
    #pragma unroll
    for (int i = 0; i < 4; ++i) {
        int m = ty + (i << 4);
        #pragma unroll
        for (int jj = 0; jj < 4; ++jj) {
            int g = n0 + (tx << 2) + jj;
            Pb[(size_t)m * NOUTP + g] = acc[i][jj];
        }
    }
}

__global__ void up_reduce(const float* __restrict__ part, const float* __restrict__ ub,
                          float* __restrict__ out) {
    int idx = blockIdx.x * blockDim.x + threadIdx.x;
    if (idx >= BB * NOUT) return;
    int b = idx / NOUT, o = idx % NOUT;
    float acc = ub[o];
    #pragma unroll
    for (int ks = 0; ks < KSPL; ++ks)
        acc += part[((size_t)ks * BB + b) * NOUTP + o];
    out[(size_t)b * NOUT + o] = acc;
}

extern "C" void kernel_launch(void* const* d_in, const int* in_sizes, int n_in,
                              void* d_out, int out_size, void* d_ws, size_t ws_size,
                              hipStream_t stream) {
    const float* x        = (const float*)d_in[0];
    const int*   lens     = (const int*)d_in[1];
    const float* conv_w   = (const float*)d_in[2];
    const float* conv_b   = (const float*)d_in[3];
    const float* wih0     = (const float*)d_in[4];
    const float* wih_rest = (const float*)d_in[5];
    const float* whh      = (const float*)d_in[6];
    const float* bih      = (const float*)d_in[7];
    const float* bhh      = (const float*)d_in[8];
    const float* post_w   = (const float*)d_in[9];
    const float* post_b   = (const float*)d_in[10];
    const float* up_w     = (const float*)d_in[11];
    const float* up_b     = (const float*)d_in[12];
    float* out = (float*)d_out;
    (void)in_sizes; (void)n_in; (void)out_size;

    auto pad = [](size_t v) { return (v + 255) & ~(size_t)255; };
    const size_t szMel   = (size_t)BB * SS * MEL * 2;
    const size_t szH     = (size_t)BB * SS * HH * 2;
    const size_t szWmf   = (size_t)NL * NCG * NKS * 64 * 16;
    const size_t szBsum  = (size_t)NL * G4 * 4;
    const size_t szState = (size_t)NL * BB * HH * 4;
    const size_t szLast  = (size_t)BB * HH * 4;
    const size_t szPost  = (size_t)BB * NPOST * 4;
    const size_t szPart  = (size_t)KSPL * BB * NOUTP * 4;

    size_t commonSmall = 2 * pad(szWmf) + pad(szBsum) + 2 * pad(szState) +
                         pad(szLast) + pad(szPost) + pad(szPart) + 4096;
    size_t needWF = pad(szMel) + 4 * pad(szH) + commonSmall;
    int wavefront = (ws_size >= needWF) ? 1 : 0;

    char* wsp = (char*)d_ws;
    size_t off = 0;
    auto alloc = [&](size_t bytes) -> void* {
        void* p = wsp + off;
        off = (off + bytes + 255) & ~(size_t)255;
        return p;
    };

    __half* melF = (__half*)alloc(szMel);
    __half* hbuf[NL];
    if (wavefront) {
        for (int l = 0; l < NL; ++l) hbuf[l] = (__half*)alloc(szH);
    } else {
        __half* p0 = (__half*)alloc(szH);
        __half* p1 = (__half*)alloc(szH);
        hbuf[0] = p0; hbuf[1] = p1; hbuf[2] = p0; hbuf[3] = p1;
    }
    uint4* wmf  = (uint4*)alloc(szWmf);
    uint4* wmfI = (uint4*)alloc(szWmf);
    float* bsum  = (float*)alloc(szBsum);
    float* hstates = (float*)alloc(szState);
    float* cstates = (float*)alloc(szState);
    float* lastb = (float*)alloc(szLast);
    float* postb = (float*)alloc(szPost);
    float* partb = (float*)alloc(szPart);

    prep_wmf<<<(NL * NCG * NKS * 64 + 255) / 256, 256, 0, stream>>>(whh, wmf);
    prep_wmfI<<<(NL * NCG * NKS * 64 + 255) / 256, 256, 0, stream>>>(wih0, wih_rest, wmfI);
    prep_bsum<<<(NL * G4 + 255) / 256, 256, 0, stream>>>(bih, bhh, bsum);

    {
        __half* m0 = hbuf[0];
        __half* m1 = (__half*)((char*)hbuf[0] + pad(szMel));
        mel_block<float><<<dim3(BB, SS / TT), 256, 0, stream>>>(x, m0, conv_w + 0 * 900, conv_b + 0 * 60);
        mel_block<__half><<<dim3(BB, SS / TT), 256, 0, stream>>>(m0, m1, conv_w + 1 * 900, conv_b + 1 * 60);
        mel_block<__half><<<dim3(BB, SS / TT), 256, 0, stream>>>(m1, melF, conv_w + 2 * 900, conv_b + 2 * 60);
    }

    auto setJob = [&](ScanArgs& sa, int nj, int l, int c) {
        sa.A[nj]    = (l == 0) ? melF : hbuf[l - 1];
        sa.K[nj]    = (l == 0) ? MEL : HH;
        sa.wmfi[nj] = wmfI + (size_t)l * NCG * NKS * 64;
        sa.wmf[nj]  = wmf + (size_t)l * NCG * NKS * 64;
        sa.bs[nj]   = bsum + l * G4;
        sa.hout[nj] = hbuf[l];
        sa.hst[nj]  = hstates + (size_t)l * BB * HH;
        sa.cst[nj]  = cstates + (size_t)l * BB * HH;
        sa.t0[nj]   = c * CH;
    };

    if (wavefront) {
        for (int w = 0; w < NCH + NL - 1; ++w) {
            ScanArgs sa{};
            int njs = 0;
            for (int l = 0; l < NL; ++l) {
                int c = w - l;
                if (c < 0 || c >= NCH) continue;
                setJob(sa, njs++, l, c);
            }
            if (njs) lstm_scan<<<dim3(njs * BB), 768, 0, stream>>>(sa);
        }
    } else {
        for (int l = 0; l < NL; ++l) {
            for (int c = 0; c < NCH; ++c) {
                ScanArgs sa{};
                setJob(sa, 0, l, c);
                lstm_scan<<<dim3(BB), 768, 0, stream>>>(sa);
            }
        }
    }

    gather_last<<<(BB * HH + 255) / 256, 256, 0, stream>>>(hbuf[NL - 1], lens, lastb);
    post_gemm<<<NPOST / 64, 256, 0, stream>>>(lastb, post_w, post_b, postb);
    up_gemm<<<dim3(NOUTP / 64, KSPL), 256, 0, stream>>>(postb, up_w, partb);
    up_reduce<<<(BB * NOUT + 255) / 256, 256, 0, stream>>>(partb, up_b, out);
}

// Round 18
// 2051.121 us; speedup vs baseline: 1.6918x; 1.6918x over previous
//
#include <hip/hip_runtime.h>
#include <hip/hip_fp16.h>

#define BB 64
#define SS 1024
#define MEL 60
#define HH 180
#define G4 720    // 4*H
#define G4P 768   // padded column count (48 groups of 16)
#define NCG 48    // column groups
#define NKS 6     // k-steps of 32 (KP=192)
#define KP 192
#define NL 4
#define NPOST 8192
#define NOUT 300
#define NOUTP 320
#define KSPL 16
#define TT 128
#define CH 64
#define NCH (SS / CH)
#define KPAIR 96

typedef _Float16 f16x8 __attribute__((ext_vector_type(8)));
typedef float f32x4 __attribute__((ext_vector_type(4)));

#if defined(__has_builtin)
#if __has_builtin(__builtin_amdgcn_fdot2)
#define HAVE_FDOT2 1
#endif
#if __has_builtin(__builtin_amdgcn_rcpf)
#define HAVE_RCPF 1
#endif
#endif
#ifndef HAVE_FDOT2
#define HAVE_FDOT2 0
#endif
#ifndef HAVE_RCPF
#define HAVE_RCPF 0
#endif

__device__ __forceinline__ float fdot2u(unsigned int w, unsigned int h, float acc) {
#if HAVE_FDOT2
    typedef _Float16 h2_t __attribute__((ext_vector_type(2)));
    union U { unsigned int u; h2_t v; };
    U a, b;
    a.u = w; b.u = h;
    return __builtin_amdgcn_fdot2(a.v, b.v, acc, false);
#else
    __half2 aw = *reinterpret_cast<const __half2*>(&w);
    __half2 ah = *reinterpret_cast<const __half2*>(&h);
    acc += __half2float(__low2half(aw)) * __half2float(__low2half(ah));
    acc += __half2float(__high2half(aw)) * __half2float(__high2half(ah));
    return acc;
#endif
}

__device__ __forceinline__ float fast_rcp(float x) {
#if HAVE_RCPF
    return __builtin_amdgcn_rcpf(x);   // v_rcp_f32, ~1ulp — output is f16-bound anyway
#else
    return 1.f / x;
#endif
}
__device__ __forceinline__ float fsigm(float x) { return fast_rcp(1.f + __expf(-x)); }
__device__ __forceinline__ float ftanh(float x) { return 1.f - 2.f * fast_rcp(__expf(2.f * x) + 1.f); }

union WU { uint4 u; f16x8 f; };

// ---------------- prep ----------------
// MFMA weight fragments: wmf[l][cg][ks][lane] = uint4 of 8 f16:
//   W[k = ks*32 + (lane>>4)*8 + j][col = cg*16 + (lane&15)], zero-padded. (r7-verified)
__global__ void prep_wmf(const float* __restrict__ whh, uint4* __restrict__ wmf) {
    int idx = blockIdx.x * blockDim.x + threadIdx.x;
    int total = NL * NCG * NKS * 64;
    if (idx >= total) return;
    int l = idx / (NCG * NKS * 64);
    int r = idx % (NCG * NKS * 64);
    int cg = r / (NKS * 64);
    int r2 = r % (NKS * 64);
    int ks = r2 / 64, lane = r2 % 64;
    int col = cg * 16 + (lane & 15);
    unsigned short v[8];
    #pragma unroll
    for (int j = 0; j < 8; ++j) {
        int k = ks * 32 + ((lane >> 4) << 3) + j;
        float f = (k < HH && col < G4) ? whh[((size_t)l * G4 + col) * HH + k] : 0.f;
        v[j] = __half_as_ushort(__float2half(f));
    }
    uint4 u;
    u.x = (unsigned)v[0] | ((unsigned)v[1] << 16);
    u.y = (unsigned)v[2] | ((unsigned)v[3] << 16);
    u.z = (unsigned)v[4] | ((unsigned)v[5] << 16);
    u.w = (unsigned)v[6] | ((unsigned)v[7] << 16);
    wmf[idx] = u;
}

// wih16: [l][g][kp] uint = packed f16 pair; zero beyond K (r7-verified)
__global__ void prep_wih16(const float* __restrict__ wih0, const float* __restrict__ wih_rest,
                           unsigned int* __restrict__ w) {
    int idx = blockIdx.x * blockDim.x + threadIdx.x;
    int total = NL * G4 * KPAIR;
    if (idx >= total) return;
    int l = idx / (G4 * KPAIR);
    int r = idx % (G4 * KPAIR);
    int g = r / KPAIR, kp = r % KPAIR;
    int K = (l == 0) ? MEL : HH;
    const float* src = (l == 0) ? (wih0 + (size_t)g * MEL)
                                : (wih_rest + ((size_t)(l - 1) * G4 + g) * HH);
    float a = 0.f, b = 0.f;
    if (2 * kp < K) { a = src[2 * kp]; b = src[2 * kp + 1]; }
    __half2 h2 = __floats2half2_rn(a, b);
    w[idx] = *(unsigned int*)&h2;
}

__global__ void prep_bsum(const float* __restrict__ bih, const float* __restrict__ bhh,
                          float* __restrict__ bsum) {
    int idx = blockIdx.x * blockDim.x + threadIdx.x;
    if (idx >= NL * G4) return;
    bsum[idx] = bih[idx] + bhh[idx];
}

// ---------------- mel smooth residual block ----------------
template <typename TIN>
__global__ __launch_bounds__(256) void mel_block(const TIN* __restrict__ in,
                                                 __half* __restrict__ out,
                                                 const float* __restrict__ w,
                                                 const float* __restrict__ bias) {
    __shared__ float xt[TT + 4][MEL];
    __shared__ float ws[900];
    __shared__ float bs[MEL];
    int bb = blockIdx.x;
    int t0 = blockIdx.y * TT;
    int tid = threadIdx.x;
    const TIN* inb = in + (size_t)bb * SS * MEL;
    for (int idx = tid; idx < (TT + 4) * MEL; idx += 256) {
        int tt = idx / MEL, ch = idx % MEL;
        int t = t0 + tt - 2;
        xt[tt][ch] = (t >= 0 && t < SS) ? (float)inb[(size_t)t * MEL + ch] : 0.f;
    }
    for (int idx = tid; idx < 900; idx += 256) ws[idx] = w[idx];
    if (tid < MEL) bs[tid] = bias[(tid % 3) * 20 + tid / 3];
    __syncthreads();
    for (int idx = tid; idx < TT * MEL; idx += 256) {
        int tt = idx / MEL, ch = idx % MEL;
        int i = ch / 3, j = ch % 3;
        int qb = 3 * i + (j - 1);
        float acc = bs[ch];
        #pragma unroll
        for (int c = 0; c < 3; ++c) {
            int q = qb + c;
            if (q >= 0 && q < MEL) {
                const float* wp = ws + ((j * 20 + i) * 3 + c) * 5;
                #pragma unroll
                for (int k = 0; k < 5; ++k) acc += xt[tt + k][q] * wp[k];
            }
        }
        out[(size_t)bb * SS * MEL + (size_t)(t0 + tt) * MEL + ch] =
            __float2half(acc + xt[tt + 2][ch]);
    }
}

// ---------------- f16 input GEMM (multi-job, r7-verified) ----------------
struct GemmArgs {
    const __half* A[16];
    const unsigned int* W[16];
    const float* bs[16];
    __half* C[16];
    size_t cbs[16];
    int K[16];
    int KT[16];
    int t0[16];
};

__global__ __launch_bounds__(256) void gemm_pre(GemmArgs ga) {
    int j = blockIdx.z;
    int K = ga.K[j], KT = ga.KT[j];
    const __half* Ab = ga.A[j] + ((size_t)blockIdx.x * SS + ga.t0[j]) * K;
    __half* Cb = ga.C[j] + (size_t)blockIdx.x * ga.cbs[j];
    const unsigned int* Wj = ga.W[j];
    const float* bsum = ga.bs[j];
    __shared__ unsigned int A16[8][72];
    __shared__ unsigned int W16[8][72];
    int n0 = blockIdx.y * 64;
    int tid = threadIdx.x;
    int tx = tid & 15, ty = tid >> 4;
    int kpl = tid & 7, mg = tid >> 3;
    float acc[4][4];
    #pragma unroll
    for (int i = 0; i < 4; ++i)
        #pragma unroll
        for (int jn = 0; jn < 4; ++jn) acc[i][jn] = 0.f;

    for (int kt = 0; kt < KT; ++kt) {
        int kp = kt * 8 + kpl;
        #pragma unroll
        for (int r = 0; r < 2; ++r) {
            int m = mg + 32 * r;
            unsigned int av = 0u;
            if (2 * kp < K) av = *(const unsigned int*)(Ab + (size_t)m * K + 2 * kp);
            A16[kpl][m] = av;
            int g = n0 + m;
            W16[kpl][m] = (g < G4) ? Wj[(size_t)g * KPAIR + kp] : 0u;
        }
        __syncthreads();
        #pragma unroll
        for (int k = 0; k < 8; ++k) {
            unsigned int a[4], b[4];
            #pragma unroll
            for (int i = 0; i < 4; ++i) a[i] = A16[k][ty + (i << 4)];
            #pragma unroll
            for (int jn = 0; jn < 4; ++jn) b[jn] = W16[k][(tx << 2) + jn];
            #pragma unroll
            for (int i = 0; i < 4; ++i)
                #pragma unroll
                for (int jn = 0; jn < 4; ++jn) acc[i][jn] = fdot2u(b[jn], a[i], acc[i][jn]);
        }
        __syncthreads();
    }
    int g0 = n0 + (tx << 2);
    if (g0 < G4) {
        #pragma unroll
        for (int i = 0; i < 4; ++i) {
            int m = ty + (i << 4);
            __half2 p0 = __floats2half2_rn(acc[i][0] + bsum[g0], acc[i][1] + bsum[g0 + 1]);
            __half2 p1 = __floats2half2_rn(acc[i][2] + bsum[g0 + 2], acc[i][3] + bsum[g0 + 3]);
            *(__half2*)(Cb + (size_t)m * G4 + g0) = p0;
            *(__half2*)(Cb + (size_t)m * G4 + g0 + 2) = p1;
        }
    }
}

// ---------------- LSTM scan: MFMA recurrent matvec, weights in AGPR/VGPR (r7/r15-verified) ----------------
struct ScanArgs {
    const __half* pre[NL];
    size_t pbs[NL];
    const uint4* wmf[NL];
    __half* hout[NL];
    float* hst[NL];
    float* cst[NL];
    int t0[NL];
};

__global__ __launch_bounds__(768) __attribute__((amdgpu_waves_per_eu(3, 3)))
void lstm_scan(ScanArgs sa) {
    int j = blockIdx.x / BB, b = blockIdx.x % BB;
    int tid = threadIdx.x;
    int wv = tid >> 6, lane = tid & 63;
    int t0 = sa.t0[j];
    const __half* preb = sa.pre[j] + (size_t)b * sa.pbs[j];
    const uint4* wmf = sa.wmf[j];
    __half* houtb = sa.hout[j] + ((size_t)b * SS + (size_t)t0) * HH;
    float* hstb = sa.hst[j] + b * HH;
    float* cstb = sa.cst[j] + b * HH;

    __shared__ __align__(16) unsigned short hs[KP];  // h state, f16
    __shared__ float gates[G4P];

    // 24 weight fragments per thread (4 col-groups x 6 k-steps), loaded once per chunk.
    uint4 wfr[24];
    #pragma unroll
    for (int q = 0; q < 4; ++q)
        #pragma unroll
        for (int ks = 0; ks < NKS; ++ks)
            wfr[q * NKS + ks] = wmf[(((size_t)(wv * 4 + q)) * NKS + ks) * 64 + lane];
    #pragma unroll
    for (int r = 0; r < 24; ++r)
        asm volatile("" : "+v"(wfr[r].x), "+v"(wfr[r].y), "+v"(wfr[r].z), "+v"(wfr[r].w));

    float c = 0.f, hlast = 0.f;
    if (tid < KP) {
        float hv = 0.f;
        if (t0 > 0 && tid < HH) { hv = hstb[tid]; c = cstb[tid]; }
        hs[tid] = __half_as_ushort(__float2half(hv));
    }
    __syncthreads();

    // pre prefetch (nonlin threads)
    float pc0 = 0.f, pc1 = 0.f, pc2 = 0.f, pc3 = 0.f;
    if (tid < HH) {
        pc0 = __half2float(preb[tid]);
        pc1 = __half2float(preb[HH + tid]);
        pc2 = __half2float(preb[2 * HH + tid]);
        pc3 = __half2float(preb[3 * HH + tid]);
    }

    int hoff = (lane >> 4) << 4;  // byte offset of this lane-group's 8 f16 within a k-step
    for (int t = 0; t < CH; ++t) {
        float pn0 = 0.f, pn1 = 0.f, pn2 = 0.f, pn3 = 0.f;
        if (tid < HH && t + 1 < CH) {
            const __half* pp = preb + (size_t)(t + 1) * G4 + tid;
            pn0 = __half2float(pp[0]);
            pn1 = __half2float(pp[HH]);
            pn2 = __half2float(pp[2 * HH]);
            pn3 = __half2float(pp[3 * HH]);
        }
        f16x8 hf[NKS];
        #pragma unroll
        for (int ks = 0; ks < NKS; ++ks) {
            WU hu;
            hu.u = *(const uint4*)((const char*)hs + ks * 64 + hoff);
            hf[ks] = hu.f;
        }
        f32x4 acc0 = {0.f, 0.f, 0.f, 0.f}, acc1 = acc0, acc2 = acc0, acc3 = acc0;
        #pragma unroll
        for (int ks = 0; ks < NKS; ++ks) {
            WU w0, w1, w2, w3;
            w0.u = wfr[0 * NKS + ks]; w1.u = wfr[1 * NKS + ks];
            w2.u = wfr[2 * NKS + ks]; w3.u = wfr[3 * NKS + ks];
            acc0 = __builtin_amdgcn_mfma_f32_16x16x32_f16(hf[ks], w0.f, acc0, 0, 0, 0);
            acc1 = __builtin_amdgcn_mfma_f32_16x16x32_f16(hf[ks], w1.f, acc1, 0, 0, 0);
            acc2 = __builtin_amdgcn_mfma_f32_16x16x32_f16(hf[ks], w2.f, acc2, 0, 0, 0);
            acc3 = __builtin_amdgcn_mfma_f32_16x16x32_f16(hf[ks], w3.f, acc3, 0, 0, 0);
        }
        if (lane < 16) {
            gates[(wv * 4 + 0) * 16 + lane] = acc0[0];
            gates[(wv * 4 + 1) * 16 + lane] = acc1[0];
            gates[(wv * 4 + 2) * 16 + lane] = acc2[0];
            gates[(wv * 4 + 3) * 16 + lane] = acc3[0];
        }
        __syncthreads();
        if (tid < HH) {
            float gi = gates[tid] + pc0;
            float gf = gates[HH + tid] + pc1;
            float gg = gates[2 * HH + tid] + pc2;
            float go = gates[3 * HH + tid] + pc3;
            float si = fsigm(gi);
            float sf = fsigm(gf);
            float so = fsigm(go);
            float tg = ftanh(gg);
            c = sf * c + si * tg;
            float hn = so * ftanh(c);
            __half hh = __float2half(hn);
            hs[tid] = __half_as_ushort(hh);
            hlast = __half2float(hh);
            houtb[(size_t)t * HH + tid] = hh;
        }
        __syncthreads();
        pc0 = pn0; pc1 = pn1; pc2 = pn2; pc3 = pn3;
    }
    if (tid < HH) { hstb[tid] = hlast; cstb[tid] = c; }
}

// ---------------- epilogue ----------------
__global__ void gather_last(const __half* __restrict__ hfin, const int* __restrict__ lens,
                            float* __restrict__ last) {
    int idx = blockIdx.x * blockDim.x + threadIdx.x;
    if (idx >= BB * HH) return;
    int b = idx / HH, d = idx % HH;
    int t = lens[b] - 1;
    t = t < 0 ? 0 : (t > SS - 1 ? SS - 1 : t);
    last[idx] = __half2float(hfin[((size_t)b * SS + t) * HH + d]);
}

__global__ __launch_bounds__(256) void post_gemm(const float* __restrict__ A,
                                                 const float* __restrict__ Bw,
                                                 const float* __restrict__ pb,
                                                 float* __restrict__ Cb) {
    __shared__ float As[16][68];
    __shared__ float Bs[16][68];
    int n0 = blockIdx.x * 64;
    int tid = threadIdx.x;
    int kk = tid & 15, q = tid >> 4;
    int tx = tid & 15, ty = tid >> 4;
    float acc[4][4];
    #pragma unroll
    for (int i = 0; i < 4; ++i)
        #pragma unroll
        for (int jj = 0; jj < 4; ++jj) acc[i][jj] = 0.f;
    for (int kt = 0; kt < 12; ++kt) {
        int kidx = kt * 16 + kk;
        bool kval = kidx < HH;
        #pragma unroll
        for (int r = 0; r < 4; ++r)
            As[kk][q + (r << 4)] = kval ? A[(size_t)(q + (r << 4)) * HH + kidx] : 0.f;
        #pragma unroll
        for (int r = 0; r < 4; ++r)
            Bs[kk][q + (r << 4)] = kval ? Bw[(size_t)(n0 + q + (r << 4)) * HH + kidx] : 0.f;
        __syncthreads();
        #pragma unroll
        for (int k = 0; k < 16; ++k) {
            float a[4], bv[4];
            #pragma unroll
            for (int i = 0; i < 4; ++i) a[i] = As[k][ty + (i << 4)];
            #pragma unroll
            for (int jj = 0; jj < 4; ++jj) bv[jj] = Bs[k][(tx << 2) + jj];
            #pragma unroll
            for (int i = 0; i < 4; ++i)
                #pragma unroll
                for (int jj = 0; jj < 4; ++jj) acc[i][jj] = fmaf(a[i], bv[jj], acc[i][jj]);
        }
        __syncthreads();
    }
    #pragma unroll
    for (int i = 0; i < 4; ++i) {
        int m = ty + (i << 4);
        #pragma unroll
        for (int jj = 0; jj < 4; ++jj) {
            int g = n0 + (tx << 2) + jj;
            float v = acc[i][jj] + pb[g];
            Cb[(size_t)m * NPOST + g] = v > 0.f ? v : 0.01f * v;
        }
    }
}

__global__ __launch_bounds__(256) void up_gemm(const float* __restrict__ A,
                                               const float* __restrict__ Bw,
                                               float* __restrict__ part) {
    __shared__ float As[16][68];
    __shared__ float Bs[16][68];
    int n0 = blockIdx.x * 64;
    int k0 = blockIdx.y * (NPOST / KSPL);
    float* Pb = part + (size_t)blockIdx.y * BB * NOUTP;
    int tid = threadIdx.x;
    int kk = tid & 15, q = tid >> 4;
    int tx = tid & 15, ty = tid >> 4;
    float acc[4][4];
    #pragma unroll
    for (int i = 0; i < 4; ++i)
        #pragma unroll
        for (int jj = 0; jj < 4; ++jj) acc[i][jj] = 0.f;
    for (int kt = 0; kt < (NPOST / KSPL) / 16; ++kt) {
        int kidx = k0 + kt * 16 + kk;
        #pragma unroll
        for (int r = 0; r < 4; ++r)
            As[kk][q + (r << 4)] = A[(size_t)(q + (r << 4)) * NPOST + kidx];
        #pragma unroll
        for (int r = 0; r < 4; ++r) {
            int g = n0 + q + (r << 4);
            Bs[kk][q + (r << 4)] = (g < NOUT) ? Bw[(size_t)g * NPOST + kidx] : 0.f;
        }
        __syncthreads();
        #pragma unroll
        for (int k = 0; k < 16; ++k) {
            float a[4], bv[4];
            #pragma unroll
            for (int i = 0; i < 4; ++i) a[i] = As[k][ty + (i << 4)];
            #pragma unroll
            for (int jj = 0; jj < 4; ++jj) bv[jj] = Bs[k][(tx << 2) + jj];
            #pragma unroll
            for (int i = 0; i < 4; ++i)
                #pragma unroll
                for (int jj = 0; jj < 4; ++jj) acc[i][jj] = fmaf(a[i], bv[jj], acc[i][jj]);
        }
        __syncthreads();
    }
    #pragma unroll
    for (int i = 0; i < 4; ++i) {
        int m = ty + (i << 4);
        #pragma unroll
        for (int jj = 0; jj < 4; ++jj) {
            int g = n0 + (tx << 2) + jj;
            Pb[(size_t)m * NOUTP + g] = acc[i][jj];
        }
    }
}

__global__ void up_reduce(const float* __restrict__ part, const float* __restrict__ ub,
                          float* __restrict__ out) {
    int idx = blockIdx.x * blockDim.x + threadIdx.x;
    if (idx >= BB * NOUT) return;
    int b = idx / NOUT, o = idx % NOUT;
    float acc = ub[o];
    #pragma unroll
    for (int ks = 0; ks < KSPL; ++ks)
        acc += part[((size_t)ks * BB + b) * NOUTP + o];
    out[(size_t)b * NOUT + o] = acc;
}

extern "C" void kernel_launch(void* const* d_in, const int* in_sizes, int n_in,
                              void* d_out, int out_size, void* d_ws, size_t ws_size,
                              hipStream_t stream) {
    const float* x        = (const float*)d_in[0];
    const int*   lens     = (const int*)d_in[1];
    const float* conv_w   = (const float*)d_in[2];
    const float* conv_b   = (const float*)d_in[3];
    const float* wih0     = (const float*)d_in[4];
    const float* wih_rest = (const float*)d_in[5];
    const float* whh      = (const float*)d_in[6];
    const float* bih      = (const float*)d_in[7];
    const float* bhh      = (const float*)d_in[8];
    const float* post_w   = (const float*)d_in[9];
    const float* post_b   = (const float*)d_in[10];
    const float* up_w     = (const float*)d_in[11];
    const float* up_b     = (const float*)d_in[12];
    float* out = (float*)d_out;
    (void)in_sizes; (void)n_in; (void)out_size;

    auto pad = [](size_t v) { return (v + 255) & ~(size_t)255; };
    const size_t szMel   = (size_t)BB * SS * MEL * 2;
    const size_t szH     = (size_t)BB * SS * HH * 2;
    const size_t szPre0  = (size_t)BB * SS * G4 * 2;        // 94.4 MB f16 (full layer-0 pre)
    const size_t szSlot  = (size_t)BB * CH * G4 * 2;        // 5.9 MB  f16
    const size_t szWmf   = (size_t)NL * NCG * NKS * 64 * 16;
    const size_t szWih   = (size_t)NL * G4 * KPAIR * 4;
    const size_t szBsum  = (size_t)NL * G4 * 4;
    const size_t szState = (size_t)NL * BB * HH * 4;
    const size_t szLast  = (size_t)BB * HH * 4;
    const size_t szPost  = (size_t)BB * NPOST * 4;
    const size_t szPart  = (size_t)KSPL * BB * NOUTP * 4;

    size_t commonSmall = pad(szWmf) + pad(szWih) + pad(szBsum) + 2 * pad(szState) +
                         pad(szLast) + pad(szPost) + pad(szPart) + 4096;
    size_t need1 = pad(szMel) + 4 * pad(szH) + pad(szPre0) + 3 * pad(szSlot) + commonSmall;
    size_t need2 = pad(szMel) + 4 * pad(szH) + 4 * pad(szSlot) + commonSmall;
    int tier = (ws_size >= need1) ? 1 : ((ws_size >= need2) ? 2 : 3);

    char* wsp = (char*)d_ws;
    size_t off = 0;
    auto alloc = [&](size_t bytes) -> void* {
        void* p = wsp + off;
        off = (off + bytes + 255) & ~(size_t)255;
        return p;
    };

    __half* melF = (__half*)alloc(szMel);
    __half* hbuf[NL];
    if (tier <= 2) {
        for (int l = 0; l < NL; ++l) hbuf[l] = (__half*)alloc(szH);
    } else {
        __half* p0 = (__half*)alloc(szH);
        __half* p1 = (__half*)alloc(szH);
        hbuf[0] = p0; hbuf[1] = p1; hbuf[2] = p0; hbuf[3] = p1;
    }
    __half* pre0 = nullptr;
    __half* slot[NL] = {nullptr, nullptr, nullptr, nullptr};
    if (tier == 1) {
        pre0 = (__half*)alloc(szPre0);
        for (int l = 1; l < NL; ++l) slot[l] = (__half*)alloc(szSlot);
    } else if (tier == 2) {
        for (int l = 0; l < NL; ++l) slot[l] = (__half*)alloc(szSlot);
    } else {
        slot[0] = (__half*)alloc(szSlot);
        for (int l = 1; l < NL; ++l) slot[l] = slot[0];
    }
    uint4* wmf = (uint4*)alloc(szWmf);
    unsigned int* wih16 = (unsigned int*)alloc(szWih);
    float* bsum  = (float*)alloc(szBsum);
    float* hstates = (float*)alloc(szState);
    float* cstates = (float*)alloc(szState);
    float* lastb = (float*)alloc(szLast);
    float* postb = (float*)alloc(szPost);
    float* partb = (float*)alloc(szPart);

    prep_wmf<<<(NL * NCG * NKS * 64 + 255) / 256, 256, 0, stream>>>(whh, wmf);
    prep_wih16<<<(NL * G4 * KPAIR + 255) / 256, 256, 0, stream>>>(wih0, wih_rest, wih16);
    prep_bsum<<<(NL * G4 + 255) / 256, 256, 0, stream>>>(bih, bhh, bsum);

    {
        __half* m0 = hbuf[0];
        __half* m1 = (__half*)((char*)hbuf[0] + pad(szMel));
        mel_block<float><<<dim3(BB, SS / TT), 256, 0, stream>>>(x, m0, conv_w + 0 * 900, conv_b + 0 * 60);
        mel_block<__half><<<dim3(BB, SS / TT), 256, 0, stream>>>(m0, m1, conv_w + 1 * 900, conv_b + 1 * 60);
        mel_block<__half><<<dim3(BB, SS / TT), 256, 0, stream>>>(m1, melF, conv_w + 2 * 900, conv_b + 2 * 60);
    }

    auto setGemmJob = [&](GemmArgs& ga, int nj, int l, int c) {
        ga.A[nj]  = (l == 0) ? melF : hbuf[l - 1];
        ga.K[nj]  = (l == 0) ? MEL : HH;
        ga.KT[nj] = (l == 0) ? 4 : 12;
        ga.W[nj]  = wih16 + (size_t)l * G4 * KPAIR;
        ga.bs[nj] = bsum + l * G4;
        if (tier == 1 && l == 0) {
            ga.C[nj] = pre0 + (size_t)c * CH * G4;
            ga.cbs[nj] = (size_t)SS * G4;
        } else {
            ga.C[nj] = slot[l];
            ga.cbs[nj] = (size_t)CH * G4;
        }
        ga.t0[nj] = c * CH;
    };
    auto setScanJob = [&](ScanArgs& sa, int nj, int l, int c) {
        if (tier == 1 && l == 0) {
            sa.pre[nj] = pre0 + (size_t)c * CH * G4;
            sa.pbs[nj] = (size_t)SS * G4;
        } else {
            sa.pre[nj] = slot[l];
            sa.pbs[nj] = (size_t)CH * G4;
        }
        sa.wmf[nj]  = wmf + (size_t)l * NCG * NKS * 64;
        sa.hout[nj] = hbuf[l];
        sa.hst[nj]  = hstates + (size_t)l * BB * HH;
        sa.cst[nj]  = cstates + (size_t)l * BB * HH;
        sa.t0[nj]   = c * CH;
    };

    if (tier <= 2) {
        if (tier == 1) {
            GemmArgs ga{};
            for (int c = 0; c < NCH; ++c) setGemmJob(ga, c, 0, c);
            gemm_pre<<<dim3(BB, 12, NCH), 256, 0, stream>>>(ga);
        }
        int lmin = (tier == 1) ? 1 : 0;
        for (int w = 0; w < NCH + NL - 1; ++w) {
            GemmArgs ga{};
            int njg = 0;
            for (int l = lmin; l < NL; ++l) {
                int c = w - l;
                if (c < 0 || c >= NCH) continue;
                setGemmJob(ga, njg++, l, c);
            }
            if (njg) gemm_pre<<<dim3(BB, 12, njg), 256, 0, stream>>>(ga);
            ScanArgs sa{};
            int njs = 0;
            for (int l = 0; l < NL; ++l) {
                int c = w - l;
                if (c < 0 || c >= NCH) continue;
                setScanJob(sa, njs++, l, c);
            }
            if (njs) lstm_scan<<<dim3(njs * BB), 768, 0, stream>>>(sa);
        }
    } else {
        for (int l = 0; l < NL; ++l) {
            for (int c = 0; c < NCH; ++c) {
                GemmArgs ga{}; ScanArgs sa{};
                setGemmJob(ga, 0, l, c);
                gemm_pre<<<dim3(BB, 12, 1), 256, 0, stream>>>(ga);
                setScanJob(sa, 0, l, c);
                lstm_scan<<<dim3(BB), 768, 0, stream>>>(sa);
            }
        }
    }

    gather_last<<<(BB * HH + 255) / 256, 256, 0, stream>>>(hbuf[NL - 1], lens, lastb);
    post_gemm<<<NPOST / 64, 256, 0, stream>>>(lastb, post_w, post_b, postb);
    up_gemm<<<dim3(NOUTP / 64, KSPL), 256, 0, stream>>>(postb, up_w, partb);
    up_reduce<<<(BB * NOUT + 255) / 256, 256, 0, stream>>>(partb, up_b, out);
}